// Round 2
// baseline (5098.560 us; speedup 1.0000x reference)
//
#include <hip/hip_runtime.h>

// AbsTopK SAE forward, MI355X (gfx950).
// B=4096, D=768, F=24576, K=72.
// d_out layout (fp32): x_rec[B*D] | acts_topk[B*F] | loss, l2, l2_full, l1, l0
// ws layout (small!): accum[4 doubles, 256B pad] | tv[B*72 f32] | ti[B*72 i32]  (~2.4 MB)
// l2_full partial-sum buffer lives in the x_rec region of d_out (dead until sdecode).

#define NB 4096
#define ND 768
#define NF 24576
#define KTOP 72
#define NSPLIT 4
#define CAP 4096

typedef unsigned int uint32;
typedef unsigned long long u64;

__device__ __forceinline__ float blockReduceSum256(float v, float* sred) {
  #pragma unroll
  for (int off = 32; off; off >>= 1) v += __shfl_down(v, off, 64);
  const int lane = threadIdx.x & 63, w = threadIdx.x >> 6;
  if (lane == 0) sred[w] = v;
  __syncthreads();
  float r = 0.f;
  if (threadIdx.x == 0) r = sred[0] + sred[1] + sred[2] + sred[3];
  __syncthreads();
  return r;  // valid in thread 0 only
}

// ---------------- GEMM1: latents = (x - b_dec) @ W_enc  [4096x768]@[768x24576]
// 128x128 tile, BK=8, 256 threads, 8x8 per thread, fp32 vector FMA.
__global__ __launch_bounds__(256) void gemm_enc(
    const float* __restrict__ X, const float* __restrict__ Wenc,
    const float* __restrict__ bdec, float* __restrict__ lat) {
  __shared__ float As[8][128];
  __shared__ float Bs[8][128];
  const int tid = threadIdx.x;
  const int bn = blockIdx.x * 128;  // F dir (192 tiles)
  const int bm = blockIdx.y * 128;  // B dir (32 tiles)
  const int tx = tid & 15, ty = tid >> 4;
  const int arow = tid >> 1, acol = (tid & 1) * 4;
  const int brow = tid >> 5, bcol = (tid & 31) * 4;
  const float* Ap = X + (size_t)(bm + arow) * ND + acol;
  const float* Bp = Wenc + (size_t)brow * NF + bn + bcol;
  float acc[8][8];
  #pragma unroll
  for (int i = 0; i < 8; ++i)
    #pragma unroll
    for (int j = 0; j < 8; ++j) acc[i][j] = 0.f;

  for (int k0 = 0; k0 < ND; k0 += 8) {
    float4 a  = *(const float4*)(Ap + k0);
    float4 bb = *(const float4*)(bdec + k0 + acol);
    float4 bv = *(const float4*)(Bp + (size_t)k0 * NF);
    As[acol + 0][arow] = a.x - bb.x;
    As[acol + 1][arow] = a.y - bb.y;
    As[acol + 2][arow] = a.z - bb.z;
    As[acol + 3][arow] = a.w - bb.w;
    *(float4*)&Bs[brow][bcol] = bv;
    __syncthreads();
    #pragma unroll
    for (int kk = 0; kk < 8; ++kk) {
      float ar[8], br[8];
      *(float4*)&ar[0] = *(const float4*)&As[kk][ty * 8];
      *(float4*)&ar[4] = *(const float4*)&As[kk][ty * 8 + 4];
      *(float4*)&br[0] = *(const float4*)&Bs[kk][tx * 8];
      *(float4*)&br[4] = *(const float4*)&Bs[kk][tx * 8 + 4];
      #pragma unroll
      for (int i = 0; i < 8; ++i)
        #pragma unroll
        for (int j = 0; j < 8; ++j)
          acc[i][j] = fmaf(ar[i], br[j], acc[i][j]);
    }
    __syncthreads();
  }
  #pragma unroll
  for (int i = 0; i < 8; ++i) {
    float* c = lat + (size_t)(bm + ty * 8 + i) * NF + bn + tx * 8;
    float4 v0 = {acc[i][0], acc[i][1], acc[i][2], acc[i][3]};
    float4 v1 = {acc[i][4], acc[i][5], acc[i][6], acc[i][7]};
    *(float4*)c = v0;
    *(float4*)(c + 4) = v1;
  }
}

// ---------------- GEMM2 (split-K, atomic): R += latents @ W_dec  into x_rec region
__global__ __launch_bounds__(256) void gemm_dec(
    const float* __restrict__ lat, const float* __restrict__ Wdec,
    float* __restrict__ R) {
  __shared__ float As[8][128];
  __shared__ float Bs[8][128];
  const int tid = threadIdx.x;
  const int bn = blockIdx.x * 128;        // D dir (6 tiles)
  const int bm = blockIdx.y * 128;        // B dir (32 tiles)
  const int kc = blockIdx.z;              // split-K (4)
  const int kb = kc * (NF / NSPLIT);      // 6144 per chunk
  const int tx = tid & 15, ty = tid >> 4;
  const int arow = tid >> 1, acol = (tid & 1) * 4;
  const int brow = tid >> 5, bcol = (tid & 31) * 4;
  const float* Ap = lat + (size_t)(bm + arow) * NF + kb + acol;
  const float* Bp = Wdec + (size_t)(kb + brow) * ND + bn + bcol;
  float acc[8][8];
  #pragma unroll
  for (int i = 0; i < 8; ++i)
    #pragma unroll
    for (int j = 0; j < 8; ++j) acc[i][j] = 0.f;

  for (int k0 = 0; k0 < NF / NSPLIT; k0 += 8) {
    float4 a  = *(const float4*)(Ap + k0);
    float4 bv = *(const float4*)(Bp + (size_t)k0 * ND);
    As[acol + 0][arow] = a.x;
    As[acol + 1][arow] = a.y;
    As[acol + 2][arow] = a.z;
    As[acol + 3][arow] = a.w;
    *(float4*)&Bs[brow][bcol] = bv;
    __syncthreads();
    #pragma unroll
    for (int kk = 0; kk < 8; ++kk) {
      float ar[8], br[8];
      *(float4*)&ar[0] = *(const float4*)&As[kk][ty * 8];
      *(float4*)&ar[4] = *(const float4*)&As[kk][ty * 8 + 4];
      *(float4*)&br[0] = *(const float4*)&Bs[kk][tx * 8];
      *(float4*)&br[4] = *(const float4*)&Bs[kk][tx * 8 + 4];
      #pragma unroll
      for (int i = 0; i < 8; ++i)
        #pragma unroll
        for (int j = 0; j < 8; ++j)
          acc[i][j] = fmaf(ar[i], br[j], acc[i][j]);
    }
    __syncthreads();
  }
  #pragma unroll
  for (int i = 0; i < 8; ++i) {
    float* c = R + (size_t)(bm + ty * 8 + i) * ND + bn + tx * 8;
    #pragma unroll
    for (int j = 0; j < 8; ++j) atomicAdd(&c[j], acc[i][j]);
  }
}

// ---------------- Abs-Top-72 per row via exact radix-histogram select.
// Tie-break: larger |v| first, then lower index (matches jax.lax.top_k stability).
__global__ __launch_bounds__(256) void abstopk(
    const float* __restrict__ lat, float* __restrict__ tv,
    int* __restrict__ ti, double* __restrict__ accum) {
  __shared__ uint32 hist[2048];
  __shared__ uint32 csum[256];
  __shared__ uint32 ckey[CAP];
  __shared__ int cidx[CAP];
  __shared__ int s_tb, s_above, s_out, s_cand, s_win;
  __shared__ u64 wred[4];
  __shared__ float sred[4];
  const int row = blockIdx.x, tid = threadIdx.x;
  const float* latr = lat + (size_t)row * NF;
  const uint32* keyr = (const uint32*)latr;

  // sentinel init (belt-and-braces: never leave poisoned slots)
  if (tid < KTOP) {
    tv[(size_t)row * KTOP + tid] = 0.f;
    ti[(size_t)row * KTOP + tid] = -1;
  }
  for (int i = tid; i < 2048; i += 256) hist[i] = 0;
  __syncthreads();
  for (int i = tid; i < NF; i += 256) {
    uint32 u = keyr[i] & 0x7fffffffu;      // abs bits: monotone key
    atomicAdd(&hist[u >> 20], 1u);         // top 11 bits (exp + 3 mantissa)
  }
  __syncthreads();
  {
    uint32 s = 0;
    #pragma unroll
    for (int j = 0; j < 8; ++j) s += hist[tid * 8 + j];
    csum[tid] = s;
  }
  __syncthreads();
  if (tid == 0) {
    int cum = 0, ch = 255;
    while (ch >= 0 && cum + (int)csum[ch] < KTOP) { cum += (int)csum[ch]; --ch; }
    int b = ch * 8 + 7;
    while (cum + (int)hist[b] < KTOP) { cum += (int)hist[b]; --b; }
    s_tb = b; s_above = cum; s_out = 0; s_cand = 0;
  }
  __syncthreads();
  const int tb = s_tb;
  for (int i = tid; i < NF; i += 256) {
    uint32 raw = keyr[i];
    uint32 u = raw & 0x7fffffffu;
    int b = (int)(u >> 20);
    if (b > tb) {                          // definitely in top-K
      int p = atomicAdd(&s_out, 1);
      tv[(size_t)row * KTOP + p] = __uint_as_float(raw);
      ti[(size_t)row * KTOP + p] = i;
    } else if (b == tb) {                  // boundary bin: candidate
      int c = atomicAdd(&s_cand, 1);
      if (c < CAP) { ckey[c] = u; cidx[c] = i; }
    }
  }
  __syncthreads();
  const int needed = KTOP - s_above;
  const int n = min(s_cand, CAP);
  for (int sel = 0; sel < needed; ++sel) {
    u64 best = 0;
    for (int c = tid; c < n; c += 256) {
      int ci = cidx[c];
      if (ci >= 0) {
        u64 v = ((u64)ckey[c] << 32) | (uint32)(NF - ci);  // max key, then min idx
        if (v > best) best = v;
      }
    }
    #pragma unroll
    for (int off = 32; off; off >>= 1) {
      u64 o = __shfl_down(best, off, 64);
      if (o > best) best = o;
    }
    if ((tid & 63) == 0) wred[tid >> 6] = best;
    __syncthreads();
    if (tid == 0) {
      u64 m = wred[0];
      for (int w = 1; w < 4; ++w) if (wred[w] > m) m = wred[w];
      int wi = (m == 0) ? -1 : (NF - (int)(uint32)(m & 0xffffffffu));
      s_win = wi;
      if (wi >= 0) {
        int pos = s_above + sel;
        tv[(size_t)row * KTOP + pos] = latr[wi];
        ti[(size_t)row * KTOP + pos] = wi;
      }
    }
    __syncthreads();
    const int wi = s_win;
    if (wi < 0) break;
    for (int c = tid; c < n; c += 256) if (cidx[c] == wi) cidx[c] = -1;
    __syncthreads();
  }
  __syncthreads();
  float v = (tid < KTOP) ? tv[(size_t)row * KTOP + tid] : 0.f;
  float l1sum = blockReduceSum256(fabsf(v), sred);
  float l0sum = blockReduceSum256((v != 0.f) ? 1.f : 0.f, sred);
  if (tid == 0) {
    atomicAdd(&accum[2], (double)l1sum);
    atomicAdd(&accum[3], (double)l0sum);
  }
}

// ---------------- l2_full: mean((R + b_dec - x)^2), R = latents@W_dec (in x_rec region)
__global__ __launch_bounds__(256) void l2full(
    const float* __restrict__ R, const float* __restrict__ bdec,
    const float* __restrict__ X, double* __restrict__ accum) {
  __shared__ float sred[4];
  const int n = NB * ND;
  float local = 0.f;
  for (int i = blockIdx.x * 256 + threadIdx.x; i < n; i += gridDim.x * 256) {
    float s = R[i] + bdec[i % ND] - X[i];
    local = fmaf(s, s, local);
  }
  float t = blockReduceSum256(local, sred);
  if (threadIdx.x == 0) atomicAdd(&accum[1], (double)t);
}

// ---------------- Sparse decode: x_rec = b_dec + sum_k tv_k * W_dec[ti_k,:], + l2 partial
// OVERWRITES the x_rec region (R is fully consumed by l2full before this runs).
__global__ __launch_bounds__(256) void sdecode(
    const float* __restrict__ tv, const int* __restrict__ ti,
    const float* __restrict__ Wdec, const float* __restrict__ bdec,
    const float* __restrict__ X, float* __restrict__ xrec,
    double* __restrict__ accum) {
  __shared__ float sv[KTOP];
  __shared__ int si[KTOP];
  __shared__ float sred[4];
  const int row = blockIdx.x, tid = threadIdx.x;
  if (tid < KTOP) {
    float v = tv[(size_t)row * KTOP + tid];
    int   k = ti[(size_t)row * KTOP + tid];
    sv[tid] = (k < 0) ? 0.f : v;
    si[tid] = (k < 0) ? 0 : k;
  }
  __syncthreads();
  const int c0 = tid, c1 = tid + 256, c2 = tid + 512;
  float a0 = bdec[c0], a1 = bdec[c1], a2 = bdec[c2];
  for (int k = 0; k < KTOP; ++k) {
    const float* wr = Wdec + (size_t)si[k] * ND;
    float v = sv[k];
    a0 = fmaf(v, wr[c0], a0);
    a1 = fmaf(v, wr[c1], a1);
    a2 = fmaf(v, wr[c2], a2);
  }
  float* xr = xrec + (size_t)row * ND;
  const float* xp = X + (size_t)row * ND;
  xr[c0] = a0; xr[c1] = a1; xr[c2] = a2;
  float d0 = a0 - xp[c0], d1 = a1 - xp[c1], d2 = a2 - xp[c2];
  float s = blockReduceSum256(fmaf(d0, d0, fmaf(d1, d1, d2 * d2)), sred);
  if (tid == 0) atomicAdd(&accum[0], (double)s);
}

// ---------------- scatter top-k values into zeroed dense acts
__global__ __launch_bounds__(256) void scatter(
    const float* __restrict__ tv, const int* __restrict__ ti,
    float* __restrict__ acts) {
  int g = blockIdx.x * 256 + threadIdx.x;
  if (g < NB * KTOP) {
    int r = g / KTOP;
    int f = ti[g];
    if (f >= 0) acts[(size_t)r * NF + f] = tv[g];
  }
}

// ---------------- finalize scalars
__global__ void finalize(const double* __restrict__ accum, float* __restrict__ scal) {
  if (threadIdx.x == 0 && blockIdx.x == 0) {
    double inv_bd = 1.0 / ((double)NB * (double)ND);
    double l2  = accum[0] * inv_bd;
    double l2f = accum[1] * inv_bd;
    double l1  = accum[2] / (double)NB;
    double l0  = accum[3] / (double)NB;
    scal[0] = (float)(l2 + 1e-3 * l1);
    scal[1] = (float)l2;
    scal[2] = (float)l2f;
    scal[3] = (float)l1;
    scal[4] = (float)l0;
  }
}

extern "C" void kernel_launch(void* const* d_in, const int* in_sizes, int n_in,
                              void* d_out, int out_size, void* d_ws, size_t ws_size,
                              hipStream_t stream) {
  const float* X    = (const float*)d_in[0];
  const float* Wenc = (const float*)d_in[1];
  const float* Wdec = (const float*)d_in[2];
  const float* bdec = (const float*)d_in[3];
  float* out  = (float*)d_out;
  float* xrec = out;                             // doubles as R accumulation buffer
  float* acts = out + (size_t)NB * ND;           // holds latents until overwritten
  float* scal = acts + (size_t)NB * NF;

  double* accum = (double*)d_ws;                 // 4 doubles
  float* tv  = (float*)((char*)d_ws + 256);      // B*72 values
  int*   ti  = (int*)(tv + (size_t)NB * KTOP);   // B*72 indices
  // total ws use: 256 + 4096*72*8 = ~2.36 MB

  hipMemsetAsync(d_ws, 0, 256, stream);          // zero accumulators

  gemm_enc<<<dim3(NF / 128, NB / 128), 256, 0, stream>>>(X, Wenc, bdec, acts);
  abstopk<<<NB, 256, 0, stream>>>(acts, tv, ti, accum);
  // R (l2_full accumulation) lives in the x_rec region; zero it first
  hipMemsetAsync(xrec, 0, (size_t)NB * ND * sizeof(float), stream);
  gemm_dec<<<dim3(ND / 128, NB / 128, NSPLIT), 256, 0, stream>>>(acts, Wdec, xrec);
  l2full<<<2048, 256, 0, stream>>>(xrec, bdec, X, accum);
  sdecode<<<NB, 256, 0, stream>>>(tv, ti, Wdec, bdec, X, xrec, accum);
  // latents fully consumed -> rewrite region as dense sparse acts
  hipMemsetAsync(acts, 0, (size_t)NB * NF * sizeof(float), stream);
  scatter<<<(NB * KTOP + 255) / 256, 256, 0, stream>>>(tv, ti, acts);
  finalize<<<1, 64, 0, stream>>>(accum, scal);
}

// Round 3
// 1479.487 us; speedup vs baseline: 3.4462x; 3.4462x over previous
//
#include <hip/hip_runtime.h>

// AbsTopK SAE forward, MI355X (gfx950). bf16-MFMA version.
// B=4096, D=768, F=24576, K=72.
// d_out (fp32): x_rec[B*D] | acts_topk[B*F] | loss, l2, l2_full, l1, l0
// acts region (402.6 MB) is dead until the end -> used as scratch:
//   lat_bf16[B*F]         @ byte 0         (201326592 B)
//   Wet = Wenc^T bf16     @ 201326592      (37748736 B)   [F][D]
//   Wdt = Wdec^T bf16     @ 239075328      (37748736 B)   [D][F]
//   xc  = bf16(x-b_dec)   @ 276824064      (6291456 B)    [B][D]
//   RP  = 4 split-K fp32  @ 283115520      (50331648 B)   4x[B][D]
// ws: accum[4 doubles] | tv[B*72 f32] | ti[B*72 i32]  (~2.4 MB)

#define NB 4096
#define ND 768
#define NF 24576
#define KTOP 72
#define CAP 4096

typedef unsigned int uint32;
typedef unsigned short u16;
typedef unsigned long long u64;
typedef __attribute__((ext_vector_type(8))) short short8;  // 8 bf16 = 4 VGPR
typedef __attribute__((ext_vector_type(4))) float f32x4;

__device__ __forceinline__ u16 f2bf(float f) {            // RNE f32->bf16
  uint32 u = __float_as_uint(f);
  return (u16)((u + 0x7fffu + ((u >> 16) & 1u)) >> 16);
}
__device__ __forceinline__ float bf2f(uint32 raw16) {
  return __uint_as_float(raw16 << 16);
}

#define GLDS16(gptr, lptr)                                                  \
  __builtin_amdgcn_global_load_lds(                                         \
      (const __attribute__((address_space(1))) unsigned int*)(gptr),        \
      (__attribute__((address_space(3))) unsigned int*)(lptr), 16, 0, 0)

__device__ __forceinline__ float blockReduceSum256(float v, float* sred) {
  #pragma unroll
  for (int off = 32; off; off >>= 1) v += __shfl_down(v, off, 64);
  const int lane = threadIdx.x & 63, w = threadIdx.x >> 6;
  if (lane == 0) sred[w] = v;
  __syncthreads();
  float r = 0.f;
  if (threadIdx.x == 0) r = sred[0] + sred[1] + sred[2] + sred[3];
  __syncthreads();
  return r;  // valid in thread 0 only
}

// ---------------- xc = bf16(x - b_dec)
__global__ __launch_bounds__(256) void prep_x(
    const float* __restrict__ X, const float* __restrict__ bdec,
    u16* __restrict__ xc) {
  int i = (blockIdx.x * 256 + threadIdx.x) * 4;
  float4 v = *(const float4*)&X[i];
  float4 b = *(const float4*)&bdec[i % ND];
  ushort4 o;
  o.x = f2bf(v.x - b.x); o.y = f2bf(v.y - b.y);
  o.z = f2bf(v.z - b.z); o.w = f2bf(v.w - b.w);
  *(ushort4*)&xc[i] = o;
}

// ---------------- transpose + convert: src f32 [R][C] -> dst bf16 [C][R]
__global__ __launch_bounds__(256) void transpose_cvt(
    const float* __restrict__ src, u16* __restrict__ dst, int R, int C) {
  __shared__ u16 t[64][66];
  const int c0 = blockIdx.x * 64, r0 = blockIdx.y * 64;
  for (int i = threadIdx.x; i < 1024; i += 256) {
    int r = i >> 4, c4 = (i & 15) * 4;
    float4 v = *(const float4*)&src[(size_t)(r0 + r) * C + c0 + c4];
    t[c4 + 0][r] = f2bf(v.x); t[c4 + 1][r] = f2bf(v.y);
    t[c4 + 2][r] = f2bf(v.z); t[c4 + 3][r] = f2bf(v.w);
  }
  __syncthreads();
  for (int i = threadIdx.x; i < 1024; i += 256) {
    int cc = i >> 4, r4 = (i & 15) * 4;
    ushort4 o = {t[cc][r4], t[cc][r4 + 1], t[cc][r4 + 2], t[cc][r4 + 3]};
    *(ushort4*)&dst[(size_t)(c0 + cc) * R + r0 + r4] = o;
  }
}

// ---------------- bf16 MFMA GEMM: C[M][N] = A[M][K] * Bt[N][K]^T
// 128x128 tile, 4 waves (each 64x64), BK=32, 16x16x32 MFMA.
// LDS staged via global_load_lds(16B) with pre-swizzled source so the
// ds_read_b128 fragment reads are bank-conflict-free (slot ^= (row>>1)&3).
// EPI 0: store bf16 to Cb (ldc=NF).  EPI 1: store fp32 partial to Cf slab z.
template <int EPI>
__global__ __launch_bounds__(256) void gemm_bf16(
    const u16* __restrict__ A, const u16* __restrict__ Bt, int ld, int ksplit,
    u16* __restrict__ Cb, float* __restrict__ Cf) {
  __shared__ u16 As[4096];  // [128][32] physical, swizzled slots
  __shared__ u16 Bs[4096];
  const int tid = threadIdx.x;
  const int l = tid & 63;
  const int w = tid >> 6;
  const int bn = blockIdx.x * 128;
  const int bm = blockIdx.y * 128;
  const size_t k0 = (size_t)blockIdx.z * ksplit;
  const int wr = (w >> 1) * 64;
  const int wc = (w & 1) * 64;
  // staging: thread covers phys (row=tid>>2, slot=tid&3); fetch logical slot
  const int srow = tid >> 2;
  const int sslot = (tid & 3) ^ ((tid >> 3) & 3);
  const u16* pA0 = A + (size_t)(bm + srow) * ld + k0 + sslot * 8;
  const u16* pA1 = pA0 + (size_t)64 * ld;
  const u16* pB0 = Bt + (size_t)(bn + srow) * ld + k0 + sslot * 8;
  const u16* pB1 = pB0 + (size_t)64 * ld;
  u16* lA0 = &As[w * 512];
  u16* lA1 = &As[2048 + w * 512];
  u16* lB0 = &Bs[w * 512];
  u16* lB1 = &Bs[2048 + w * 512];
  // fragment reads: row = base + fr, logical kslot = ks -> phys ks^((fr>>1)&3)
  const int fr = l & 15, ks = l >> 4;
  const int koff = (ks ^ ((fr >> 1) & 3)) * 8;

  f32x4 acc[4][4];
  #pragma unroll
  for (int m = 0; m < 4; ++m)
    #pragma unroll
    for (int n = 0; n < 4; ++n) acc[m][n] = (f32x4){0.f, 0.f, 0.f, 0.f};

  for (int kb = 0; kb < ksplit; kb += 32) {
    GLDS16(pA0 + kb, lA0);
    GLDS16(pA1 + kb, lA1);
    GLDS16(pB0 + kb, lB0);
    GLDS16(pB1 + kb, lB1);
    asm volatile("s_waitcnt vmcnt(0)" ::: "memory");
    __syncthreads();
    short8 a[4], b[4];
    #pragma unroll
    for (int m = 0; m < 4; ++m)
      a[m] = *(const short8*)&As[(wr + m * 16 + fr) * 32 + koff];
    #pragma unroll
    for (int n = 0; n < 4; ++n)
      b[n] = *(const short8*)&Bs[(wc + n * 16 + fr) * 32 + koff];
    #pragma unroll
    for (int m = 0; m < 4; ++m)
      #pragma unroll
      for (int n = 0; n < 4; ++n)
        acc[m][n] = __builtin_amdgcn_mfma_f32_16x16x32_bf16(a[m], b[n], acc[m][n], 0, 0, 0);
    __syncthreads();
  }

  // C/D layout: col = lane&15, row = (lane>>4)*4 + reg   [HW-verified]
  const int crow0 = bm + wr + (l >> 4) * 4;
  const int ccol0 = bn + wc + fr;
  #pragma unroll
  for (int m = 0; m < 4; ++m)
    #pragma unroll
    for (int n = 0; n < 4; ++n)
      #pragma unroll
      for (int q = 0; q < 4; ++q) {
        const int row = crow0 + m * 16 + q;
        const int col = ccol0 + n * 16;
        if (EPI == 0)
          Cb[(size_t)row * NF + col] = f2bf(acc[m][n][q]);
        else
          Cf[(size_t)blockIdx.z * NB * ND + (size_t)row * ND + col] = acc[m][n][q];
      }
}

// ---------------- Abs-Top-72 per row on bf16 latents (radix-histogram select).
__global__ __launch_bounds__(256) void abstopk(
    const u16* __restrict__ lat, float* __restrict__ tv,
    int* __restrict__ ti, double* __restrict__ accum) {
  __shared__ uint32 hist[2048];
  __shared__ uint32 csum[256];
  __shared__ u16 ckey[CAP];
  __shared__ int cidx[CAP];
  __shared__ int s_tb, s_above, s_out, s_cand, s_win;
  __shared__ u64 wred[4];
  __shared__ float sred[4];
  const int row = blockIdx.x, tid = threadIdx.x;
  const u16* latr = lat + (size_t)row * NF;
  const uint32* k2 = (const uint32*)latr;

  if (tid < KTOP) {
    tv[(size_t)row * KTOP + tid] = 0.f;
    ti[(size_t)row * KTOP + tid] = -1;
  }
  for (int i = tid; i < 2048; i += 256) hist[i] = 0;
  __syncthreads();
  for (int i = tid; i < NF / 2; i += 256) {
    uint32 d = k2[i];
    atomicAdd(&hist[(d & 0x7fffu) >> 4], 1u);
    atomicAdd(&hist[((d >> 16) & 0x7fffu) >> 4], 1u);
  }
  __syncthreads();
  {
    uint32 s = 0;
    #pragma unroll
    for (int j = 0; j < 8; ++j) s += hist[tid * 8 + j];
    csum[tid] = s;
  }
  __syncthreads();
  if (tid == 0) {
    int cum = 0, ch = 255;
    while (ch >= 0 && cum + (int)csum[ch] < KTOP) { cum += (int)csum[ch]; --ch; }
    int b = ch * 8 + 7;
    while (cum + (int)hist[b] < KTOP) { cum += (int)hist[b]; --b; }
    s_tb = b; s_above = cum; s_out = 0; s_cand = 0;
  }
  __syncthreads();
  const int tb = s_tb;
  for (int i = tid; i < NF / 2; i += 256) {
    uint32 d = k2[i];
    #pragma unroll
    for (int h = 0; h < 2; ++h) {
      uint32 raw = (h == 0) ? (d & 0xffffu) : (d >> 16);
      uint32 u = raw & 0x7fffu;
      int b = (int)(u >> 4);
      int idx = 2 * i + h;
      if (b > tb) {
        int p = atomicAdd(&s_out, 1);
        tv[(size_t)row * KTOP + p] = bf2f(raw);
        ti[(size_t)row * KTOP + p] = idx;
      } else if (b == tb) {
        int c = atomicAdd(&s_cand, 1);
        if (c < CAP) { ckey[c] = (u16)u; cidx[c] = idx; }
      }
    }
  }
  __syncthreads();
  const int needed = KTOP - s_above;
  const int n = min(s_cand, CAP);
  for (int sel = 0; sel < needed; ++sel) {
    u64 best = 0;
    for (int c = tid; c < n; c += 256) {
      int ci = cidx[c];
      if (ci >= 0) {
        u64 v = ((u64)ckey[c] << 32) | (uint32)(NF - ci);  // max |v|, then min idx
        if (v > best) best = v;
      }
    }
    #pragma unroll
    for (int off = 32; off; off >>= 1) {
      u64 o = __shfl_down(best, off, 64);
      if (o > best) best = o;
    }
    if ((tid & 63) == 0) wred[tid >> 6] = best;
    __syncthreads();
    if (tid == 0) {
      u64 m = wred[0];
      for (int ww = 1; ww < 4; ++ww) if (wred[ww] > m) m = wred[ww];
      int wi = (m == 0) ? -1 : (NF - (int)(uint32)(m & 0xffffffffu));
      s_win = wi;
      if (wi >= 0) {
        int pos = s_above + sel;
        tv[(size_t)row * KTOP + pos] = bf2f(latr[wi]);
        ti[(size_t)row * KTOP + pos] = wi;
      }
    }
    __syncthreads();
    const int wi = s_win;
    if (wi < 0) break;
    for (int c = tid; c < n; c += 256) if (cidx[c] == wi) cidx[c] = -1;
    __syncthreads();
  }
  __syncthreads();
  float v = (tid < KTOP) ? tv[(size_t)row * KTOP + tid] : 0.f;
  float l1sum = blockReduceSum256(fabsf(v), sred);
  float l0sum = blockReduceSum256((v != 0.f) ? 1.f : 0.f, sred);
  if (tid == 0) {
    atomicAdd(&accum[2], (double)l1sum);
    atomicAdd(&accum[3], (double)l0sum);
  }
}

// ---------------- l2_full from 4 split-K partials
__global__ __launch_bounds__(256) void l2full(
    const float* __restrict__ RP, const float* __restrict__ bdec,
    const float* __restrict__ X, double* __restrict__ accum) {
  __shared__ float sred[4];
  const int n = NB * ND;
  float local = 0.f;
  for (int i = blockIdx.x * 256 + threadIdx.x; i < n; i += gridDim.x * 256) {
    float s = RP[i] + RP[i + n] + RP[i + 2 * n] + RP[i + 3 * n]
              + bdec[i % ND] - X[i];
    local = fmaf(s, s, local);
  }
  float t = blockReduceSum256(local, sred);
  if (threadIdx.x == 0) atomicAdd(&accum[1], (double)t);
}

// ---------------- Sparse decode (fp32 exact): x_rec = b_dec + sum tv_k*W_dec[ti_k]
__global__ __launch_bounds__(256) void sdecode(
    const float* __restrict__ tv, const int* __restrict__ ti,
    const float* __restrict__ Wdec, const float* __restrict__ bdec,
    const float* __restrict__ X, float* __restrict__ xrec,
    double* __restrict__ accum) {
  __shared__ float sv[KTOP];
  __shared__ int si[KTOP];
  __shared__ float sred[4];
  const int row = blockIdx.x, tid = threadIdx.x;
  if (tid < KTOP) {
    float v = tv[(size_t)row * KTOP + tid];
    int   k = ti[(size_t)row * KTOP + tid];
    sv[tid] = (k < 0) ? 0.f : v;
    si[tid] = (k < 0) ? 0 : k;
  }
  __syncthreads();
  const int c0 = tid, c1 = tid + 256, c2 = tid + 512;
  float a0 = bdec[c0], a1 = bdec[c1], a2 = bdec[c2];
  for (int k = 0; k < KTOP; ++k) {
    const float* wr = Wdec + (size_t)si[k] * ND;
    float v = sv[k];
    a0 = fmaf(v, wr[c0], a0);
    a1 = fmaf(v, wr[c1], a1);
    a2 = fmaf(v, wr[c2], a2);
  }
  float* xr = xrec + (size_t)row * ND;
  const float* xp = X + (size_t)row * ND;
  xr[c0] = a0; xr[c1] = a1; xr[c2] = a2;
  float d0 = a0 - xp[c0], d1 = a1 - xp[c1], d2 = a2 - xp[c2];
  float s = blockReduceSum256(fmaf(d0, d0, fmaf(d1, d1, d2 * d2)), sred);
  if (tid == 0) atomicAdd(&accum[0], (double)s);
}

// ---------------- scatter top-k into zeroed dense acts
__global__ __launch_bounds__(256) void scatter(
    const float* __restrict__ tv, const int* __restrict__ ti,
    float* __restrict__ acts) {
  int g = blockIdx.x * 256 + threadIdx.x;
  if (g < NB * KTOP) {
    int r = g / KTOP;
    int f = ti[g];
    if (f >= 0) acts[(size_t)r * NF + f] = tv[g];
  }
}

// ---------------- finalize scalars
__global__ void finalize(const double* __restrict__ accum, float* __restrict__ scal) {
  if (threadIdx.x == 0 && blockIdx.x == 0) {
    double inv_bd = 1.0 / ((double)NB * (double)ND);
    double l2  = accum[0] * inv_bd;
    double l2f = accum[1] * inv_bd;
    double l1  = accum[2] / (double)NB;
    double l0  = accum[3] / (double)NB;
    scal[0] = (float)(l2 + 1e-3 * l1);
    scal[1] = (float)l2;
    scal[2] = (float)l2f;
    scal[3] = (float)l1;
    scal[4] = (float)l0;
  }
}

extern "C" void kernel_launch(void* const* d_in, const int* in_sizes, int n_in,
                              void* d_out, int out_size, void* d_ws, size_t ws_size,
                              hipStream_t stream) {
  const float* X    = (const float*)d_in[0];
  const float* Wenc = (const float*)d_in[1];
  const float* Wdec = (const float*)d_in[2];
  const float* bdec = (const float*)d_in[3];
  float* out  = (float*)d_out;
  float* xrec = out;
  float* acts = out + (size_t)NB * ND;
  float* scal = acts + (size_t)NB * NF;

  // scratch carved from the dead acts region
  u16*   lat = (u16*)acts;
  u16*   Wet = (u16*)((char*)acts + 201326592);
  u16*   Wdt = (u16*)((char*)acts + 239075328);
  u16*   xc  = (u16*)((char*)acts + 276824064);
  float* RP  = (float*)((char*)acts + 283115520);

  double* accum = (double*)d_ws;
  float* tv = (float*)((char*)d_ws + 256);
  int*   ti = (int*)(tv + (size_t)NB * KTOP);

  hipMemsetAsync(d_ws, 0, 256, stream);

  prep_x<<<NB * ND / 1024, 256, 0, stream>>>(X, bdec, xc);
  transpose_cvt<<<dim3(NF / 64, ND / 64), 256, 0, stream>>>(Wenc, Wet, ND, NF);
  gemm_bf16<0><<<dim3(NF / 128, NB / 128, 1), 256, 0, stream>>>(
      xc, Wet, ND, ND, lat, nullptr);
  abstopk<<<NB, 256, 0, stream>>>(lat, tv, ti, accum);
  transpose_cvt<<<dim3(ND / 64, NF / 64), 256, 0, stream>>>(Wdec, Wdt, NF, ND);
  gemm_bf16<1><<<dim3(ND / 128, NB / 128, 4), 256, 0, stream>>>(
      lat, Wdt, NF, NF / 4, nullptr, RP);
  l2full<<<2048, 256, 0, stream>>>(RP, bdec, X, accum);
  sdecode<<<NB, 256, 0, stream>>>(tv, ti, Wdec, bdec, X, xrec, accum);
  hipMemsetAsync(acts, 0, (size_t)NB * NF * sizeof(float), stream);
  scatter<<<(NB * KTOP + 255) / 256, 256, 0, stream>>>(tv, ti, acts);
  finalize<<<1, 64, 0, stream>>>(accum, scal);
}

// Round 4
// 1388.305 us; speedup vs baseline: 3.6725x; 1.0657x over previous
//
#include <hip/hip_runtime.h>

// AbsTopK SAE forward, MI355X (gfx950). bf16-MFMA + register-radix topk.
// B=4096, D=768, F=24576, K=72.
// d_out (fp32): x_rec[B*D] | acts_topk[B*F] | loss, l2, l2_full, l1, l0
// acts region (402.6 MB) dead until the end -> scratch:
//   lat bf16 [B][F]   @ 0          (201326592 B)
//   Wet bf16 [F][D]   @ 201326592  (37748736 B)   Wenc^T
//   Wdt bf16 [D][F]   @ 239075328  (37748736 B)   Wdec^T
//   xc  bf16 [B][D]   @ 276824064  (6291456 B)    x - b_dec
//   RP  f32 4x[B][D]  @ 283115520  (50331648 B)   split-K partials
//   Wdb bf16 [F][D]   @ 333447168  (37748736 B)   Wdec straight
// ws: accum[4 doubles] | tv[B*72 f32] | ti[B*72 i32]  (~2.4 MB)

#define NB 4096
#define ND 768
#define NF 24576
#define KTOP 72
#define TCAP 256

typedef unsigned int uint32;
typedef unsigned short u16;
typedef __attribute__((ext_vector_type(8))) short short8;
typedef __attribute__((ext_vector_type(4))) float f32x4;

__device__ __forceinline__ u16 f2bf(float f) {
  uint32 u = __float_as_uint(f);
  return (u16)((u + 0x7fffu + ((u >> 16) & 1u)) >> 16);
}
__device__ __forceinline__ float bf2f(uint32 raw16) {
  return __uint_as_float(raw16 << 16);
}

#define GLDS16(gptr, lptr)                                                  \
  __builtin_amdgcn_global_load_lds(                                         \
      (const __attribute__((address_space(1))) unsigned int*)(gptr),        \
      (__attribute__((address_space(3))) unsigned int*)(lptr), 16, 0, 0)

__device__ __forceinline__ float blockReduceSum256(float v, float* sred) {
  #pragma unroll
  for (int off = 32; off; off >>= 1) v += __shfl_down(v, off, 64);
  const int lane = threadIdx.x & 63, w = threadIdx.x >> 6;
  if (lane == 0) sred[w] = v;
  __syncthreads();
  float r = 0.f;
  if (threadIdx.x == 0) r = sred[0] + sred[1] + sred[2] + sred[3];
  __syncthreads();
  return r;  // valid in thread 0 only
}

// ---------------- xc = bf16(x - b_dec)
__global__ __launch_bounds__(256) void prep_x(
    const float* __restrict__ X, const float* __restrict__ bdec,
    u16* __restrict__ xc) {
  int i = (blockIdx.x * 256 + threadIdx.x) * 4;
  float4 v = *(const float4*)&X[i];
  float4 b = *(const float4*)&bdec[i % ND];
  ushort4 o;
  o.x = f2bf(v.x - b.x); o.y = f2bf(v.y - b.y);
  o.z = f2bf(v.z - b.z); o.w = f2bf(v.w - b.w);
  *(ushort4*)&xc[i] = o;
}

// ---------------- transpose+cvt: src f32 [R][C] -> dst bf16 [C][R]
__global__ __launch_bounds__(256) void transpose_cvt(
    const float* __restrict__ src, u16* __restrict__ dst, int R, int C) {
  __shared__ u16 t[64][66];
  const int c0 = blockIdx.x * 64, r0 = blockIdx.y * 64;
  for (int i = threadIdx.x; i < 1024; i += 256) {
    int r = i >> 4, c4 = (i & 15) * 4;
    float4 v = *(const float4*)&src[(size_t)(r0 + r) * C + c0 + c4];
    t[c4 + 0][r] = f2bf(v.x); t[c4 + 1][r] = f2bf(v.y);
    t[c4 + 2][r] = f2bf(v.z); t[c4 + 3][r] = f2bf(v.w);
  }
  __syncthreads();
  for (int i = threadIdx.x; i < 1024; i += 256) {
    int cc = i >> 4, r4 = (i & 15) * 4;
    ushort4 o = {t[cc][r4], t[cc][r4 + 1], t[cc][r4 + 2], t[cc][r4 + 3]};
    *(ushort4*)&dst[(size_t)(c0 + cc) * R + r0 + r4] = o;
  }
}

// ---------------- dual cvt for Wdec: transposed (Wdt) + straight (Wdb)
__global__ __launch_bounds__(256) void cvt_dec_dual(
    const float* __restrict__ src, u16* __restrict__ dstT,
    u16* __restrict__ dstS, int R, int C) {
  __shared__ u16 t[64][66];
  const int c0 = blockIdx.x * 64, r0 = blockIdx.y * 64;
  for (int i = threadIdx.x; i < 1024; i += 256) {
    int r = i >> 4, c4 = (i & 15) * 4;
    float4 v = *(const float4*)&src[(size_t)(r0 + r) * C + c0 + c4];
    ushort4 o = {f2bf(v.x), f2bf(v.y), f2bf(v.z), f2bf(v.w)};
    *(ushort4*)&dstS[(size_t)(r0 + r) * C + c0 + c4] = o;
    t[c4 + 0][r] = o.x; t[c4 + 1][r] = o.y;
    t[c4 + 2][r] = o.z; t[c4 + 3][r] = o.w;
  }
  __syncthreads();
  for (int i = threadIdx.x; i < 1024; i += 256) {
    int cc = i >> 4, r4 = (i & 15) * 4;
    ushort4 o = {t[cc][r4], t[cc][r4 + 1], t[cc][r4 + 2], t[cc][r4 + 3]};
    *(ushort4*)&dstT[(size_t)(c0 + cc) * R + r0 + r4] = o;
  }
}

// ---------------- bf16 MFMA GEMM: C[M][N] = A[M][K] * Bt[N][K]^T
// 128x128 tile, 4 waves (64x64 each), BK=32, 16x16x32 MFMA, swizzled LDS.
template <int EPI>
__global__ __launch_bounds__(256) void gemm_bf16(
    const u16* __restrict__ A, const u16* __restrict__ Bt, int ld, int ksplit,
    u16* __restrict__ Cb, float* __restrict__ Cf) {
  __shared__ u16 As[4096];
  __shared__ u16 Bs[4096];
  const int tid = threadIdx.x;
  const int l = tid & 63;
  const int w = tid >> 6;
  const int bn = blockIdx.x * 128;
  const int bm = blockIdx.y * 128;
  const size_t k0 = (size_t)blockIdx.z * ksplit;
  const int wr = (w >> 1) * 64;
  const int wc = (w & 1) * 64;
  const int srow = tid >> 2;
  const int sslot = (tid & 3) ^ ((tid >> 3) & 3);
  const u16* pA0 = A + (size_t)(bm + srow) * ld + k0 + sslot * 8;
  const u16* pA1 = pA0 + (size_t)64 * ld;
  const u16* pB0 = Bt + (size_t)(bn + srow) * ld + k0 + sslot * 8;
  const u16* pB1 = pB0 + (size_t)64 * ld;
  u16* lA0 = &As[w * 512];
  u16* lA1 = &As[2048 + w * 512];
  u16* lB0 = &Bs[w * 512];
  u16* lB1 = &Bs[2048 + w * 512];
  const int fr = l & 15, ks = l >> 4;
  const int koff = (ks ^ ((fr >> 1) & 3)) * 8;

  f32x4 acc[4][4];
  #pragma unroll
  for (int m = 0; m < 4; ++m)
    #pragma unroll
    for (int n = 0; n < 4; ++n) acc[m][n] = (f32x4){0.f, 0.f, 0.f, 0.f};

  for (int kb = 0; kb < ksplit; kb += 32) {
    GLDS16(pA0 + kb, lA0);
    GLDS16(pA1 + kb, lA1);
    GLDS16(pB0 + kb, lB0);
    GLDS16(pB1 + kb, lB1);
    asm volatile("s_waitcnt vmcnt(0)" ::: "memory");
    __syncthreads();
    short8 a[4], b[4];
    #pragma unroll
    for (int m = 0; m < 4; ++m)
      a[m] = *(const short8*)&As[(wr + m * 16 + fr) * 32 + koff];
    #pragma unroll
    for (int n = 0; n < 4; ++n)
      b[n] = *(const short8*)&Bs[(wc + n * 16 + fr) * 32 + koff];
    #pragma unroll
    for (int m = 0; m < 4; ++m)
      #pragma unroll
      for (int n = 0; n < 4; ++n)
        acc[m][n] = __builtin_amdgcn_mfma_f32_16x16x32_bf16(a[m], b[n], acc[m][n], 0, 0, 0);
    __syncthreads();
  }

  const int crow0 = bm + wr + (l >> 4) * 4;
  const int ccol0 = bn + wc + fr;
  #pragma unroll
  for (int m = 0; m < 4; ++m)
    #pragma unroll
    for (int n = 0; n < 4; ++n)
      #pragma unroll
      for (int q = 0; q < 4; ++q) {
        const int row = crow0 + m * 16 + q;
        const int col = ccol0 + n * 16;
        if (EPI == 0)
          Cb[(size_t)row * NF + col] = f2bf(acc[m][n][q]);
        else
          Cf[(size_t)blockIdx.z * NB * ND + (size_t)row * ND + col] = acc[m][n][q];
      }
}

// ---------------- Abs-Top-72: register-resident radix binary search.
// skey per bf16 half: ((u & 0x7fff) << 1) | sign  -> 15-bit magnitude m = skey>>1.
// m > T  <=>  skey > (T<<1|1).  Ties at m == t* filled by ascending index.
__global__ __launch_bounds__(256) void abstopk(
    const u16* __restrict__ lat, float* __restrict__ tv,
    int* __restrict__ ti, double* __restrict__ accum) {
  __shared__ int scnt[4];
  __shared__ int cidx[TCAP];
  __shared__ uint32 cs[TCAP];
  __shared__ int s_out, s_cand;
  __shared__ float sred[4];
  const int row = blockIdx.x, tid = threadIdx.x;
  float* tvr = tv + (size_t)row * KTOP;
  int* tir = ti + (size_t)row * KTOP;

  if (tid < KTOP) { tvr[tid] = 0.f; tir[tid] = -1; }
  if (tid == 0) { s_out = 0; s_cand = 0; }

  // load row: 12 x uint4 per thread, transform to skeys (stays in VGPRs)
  const uint4* rp4 = (const uint4*)(lat + (size_t)row * NF);
  uint32 s[48];
  #pragma unroll
  for (int i = 0; i < 12; ++i) {
    uint4 d = rp4[tid + i * 256];
    s[4 * i + 0] = ((d.x & 0x7fff7fffu) << 1) | ((d.x >> 15) & 0x10001u);
    s[4 * i + 1] = ((d.y & 0x7fff7fffu) << 1) | ((d.y >> 15) & 0x10001u);
    s[4 * i + 2] = ((d.z & 0x7fff7fffu) << 1) | ((d.z >> 15) & 0x10001u);
    s[4 * i + 3] = ((d.w & 0x7fff7fffu) << 1) | ((d.w >> 15) & 0x10001u);
  }
  __syncthreads();  // sentinel init visible before classify writes

  // radix-MSB search: largest t with C(t) >= K, C(t) = #{m > t}
  int t = 0;
  for (int b = 14; b >= 0; --b) {
    const uint32 tc = (uint32)t | (1u << b);
    const uint32 T2 = (tc << 1) | 1u;
    int c = 0;
    #pragma unroll
    for (int m = 0; m < 48; ++m) {
      c += ((s[m] & 0xffffu) > T2);
      c += ((s[m] >> 16) > T2);
    }
    #pragma unroll
    for (int off = 32; off; off >>= 1) c += __shfl_down(c, off, 64);
    if ((tid & 63) == 0) scnt[tid >> 6] = c;
    __syncthreads();
    c = scnt[0] + scnt[1] + scnt[2] + scnt[3];
    if (c >= KTOP) t = (int)tc;
    __syncthreads();
  }
  const uint32 tstar = (uint32)t + 1u;        // K-th largest magnitude
  const uint32 T2a = (tstar << 1) | 1u;

  // classify from registers
  float myl1 = 0.f;
  float myl0 = 0.f;
  #pragma unroll
  for (int i = 0; i < 12; ++i) {
    #pragma unroll
    for (int j = 0; j < 4; ++j) {
      const uint32 w32 = s[4 * i + j];
      #pragma unroll
      for (int h = 0; h < 2; ++h) {
        const uint32 half = h ? (w32 >> 16) : (w32 & 0xffffu);
        const int idx = 8 * (tid + i * 256) + 2 * j + h;
        if (half > T2a) {                      // m > t*: definitely in
          int p = atomicAdd(&s_out, 1);
          uint32 raw = (half >> 1) | ((half & 1u) << 15);
          float val = bf2f(raw);
          tvr[p] = val; tir[p] = idx;
          myl1 += fabsf(val); myl0 += 1.f;
        } else if ((half >> 1) == tstar) {     // tie at t*
          int cpos = atomicAdd(&s_cand, 1);
          if (cpos < TCAP) { cidx[cpos] = idx; cs[cpos] = half; }
        }
      }
    }
  }
  __syncthreads();
  const int above = s_out;
  const int needed = KTOP - above;
  const int n = min(s_cand, TCAP);
  for (int c = tid; c < n; c += 256) {
    const int my = cidx[c];
    int r = 0;
    for (int k = 0; k < n; ++k) r += (cidx[k] < my);
    if (r < needed) {
      uint32 half = cs[c];
      uint32 raw = (half >> 1) | ((half & 1u) << 15);
      float val = bf2f(raw);
      tvr[above + r] = val; tir[above + r] = my;
      myl1 += fabsf(val); myl0 += 1.f;
    }
  }
  float l1sum = blockReduceSum256(myl1, sred);
  float l0sum = blockReduceSum256(myl0, sred);
  if (tid == 0) {
    atomicAdd(&accum[2], (double)l1sum);
    atomicAdd(&accum[3], (double)l0sum);
  }
}

// ---------------- l2_full from 4 split-K partials
__global__ __launch_bounds__(256) void l2full(
    const float* __restrict__ RP, const float* __restrict__ bdec,
    const float* __restrict__ X, double* __restrict__ accum) {
  __shared__ float sred[4];
  const int n = NB * ND;
  float local = 0.f;
  for (int i = blockIdx.x * 256 + threadIdx.x; i < n; i += gridDim.x * 256) {
    float s = RP[i] + RP[i + n] + RP[i + 2 * n] + RP[i + 3 * n]
              + bdec[i % ND] - X[i];
    local = fmaf(s, s, local);
  }
  float t = blockReduceSum256(local, sred);
  if (threadIdx.x == 0) atomicAdd(&accum[1], (double)t);
}

// ---------------- Sparse decode with bf16 W_dec rows (fp32 accumulate)
__global__ __launch_bounds__(256) void sdecode(
    const float* __restrict__ tv, const int* __restrict__ ti,
    const u16* __restrict__ Wdb, const float* __restrict__ bdec,
    const float* __restrict__ X, float* __restrict__ xrec,
    double* __restrict__ accum) {
  __shared__ float sv[KTOP];
  __shared__ int si[KTOP];
  __shared__ float sred[4];
  const int row = blockIdx.x, tid = threadIdx.x;
  if (tid < KTOP) {
    float v = tv[(size_t)row * KTOP + tid];
    int   k = ti[(size_t)row * KTOP + tid];
    sv[tid] = (k < 0) ? 0.f : v;
    si[tid] = (k < 0) ? 0 : k;
  }
  __syncthreads();
  const int c0 = tid, c1 = tid + 256, c2 = tid + 512;
  float a0 = bdec[c0], a1 = bdec[c1], a2 = bdec[c2];
  for (int k = 0; k < KTOP; ++k) {
    const u16* wr = Wdb + (size_t)si[k] * ND;
    float v = sv[k];
    a0 = fmaf(v, bf2f(wr[c0]), a0);
    a1 = fmaf(v, bf2f(wr[c1]), a1);
    a2 = fmaf(v, bf2f(wr[c2]), a2);
  }
  float* xr = xrec + (size_t)row * ND;
  const float* xp = X + (size_t)row * ND;
  xr[c0] = a0; xr[c1] = a1; xr[c2] = a2;
  float d0 = a0 - xp[c0], d1 = a1 - xp[c1], d2 = a2 - xp[c2];
  float s = blockReduceSum256(fmaf(d0, d0, fmaf(d1, d1, d2 * d2)), sred);
  if (tid == 0) atomicAdd(&accum[0], (double)s);
}

// ---------------- per-row zero-fill + topk insert (replaces memset+scatter)
__global__ __launch_bounds__(256) void zeroscatter(
    const float* __restrict__ tv, const int* __restrict__ ti,
    float* __restrict__ acts) {
  const int row = blockIdx.x, tid = threadIdx.x;
  float* rp = acts + (size_t)row * NF;
  const float4 z = {0.f, 0.f, 0.f, 0.f};
  #pragma unroll
  for (int i = 0; i < 24; ++i)
    *(float4*)&rp[(i * 256 + tid) * 4] = z;
  __syncthreads();
  if (tid < KTOP) {
    int f = ti[(size_t)row * KTOP + tid];
    if (f >= 0) rp[f] = tv[(size_t)row * KTOP + tid];
  }
}

// ---------------- finalize scalars
__global__ void finalize(const double* __restrict__ accum, float* __restrict__ scal) {
  if (threadIdx.x == 0 && blockIdx.x == 0) {
    double inv_bd = 1.0 / ((double)NB * (double)ND);
    double l2  = accum[0] * inv_bd;
    double l2f = accum[1] * inv_bd;
    double l1  = accum[2] / (double)NB;
    double l0  = accum[3] / (double)NB;
    scal[0] = (float)(l2 + 1e-3 * l1);
    scal[1] = (float)l2;
    scal[2] = (float)l2f;
    scal[3] = (float)l1;
    scal[4] = (float)l0;
  }
}

extern "C" void kernel_launch(void* const* d_in, const int* in_sizes, int n_in,
                              void* d_out, int out_size, void* d_ws, size_t ws_size,
                              hipStream_t stream) {
  const float* X    = (const float*)d_in[0];
  const float* Wenc = (const float*)d_in[1];
  const float* Wdec = (const float*)d_in[2];
  const float* bdec = (const float*)d_in[3];
  float* out  = (float*)d_out;
  float* xrec = out;
  float* acts = out + (size_t)NB * ND;
  float* scal = acts + (size_t)NB * NF;

  u16*   lat = (u16*)acts;
  u16*   Wet = (u16*)((char*)acts + 201326592);
  u16*   Wdt = (u16*)((char*)acts + 239075328);
  u16*   xc  = (u16*)((char*)acts + 276824064);
  float* RP  = (float*)((char*)acts + 283115520);
  u16*   Wdb = (u16*)((char*)acts + 333447168);

  double* accum = (double*)d_ws;
  float* tv = (float*)((char*)d_ws + 256);
  int*   ti = (int*)(tv + (size_t)NB * KTOP);

  hipMemsetAsync(d_ws, 0, 256, stream);

  prep_x<<<NB * ND / 1024, 256, 0, stream>>>(X, bdec, xc);
  transpose_cvt<<<dim3(NF / 64, ND / 64), 256, 0, stream>>>(Wenc, Wet, ND, NF);
  cvt_dec_dual<<<dim3(ND / 64, NF / 64), 256, 0, stream>>>(Wdec, Wdt, Wdb, NF, ND);
  gemm_bf16<0><<<dim3(NF / 128, NB / 128, 1), 256, 0, stream>>>(
      xc, Wet, ND, ND, lat, nullptr);
  abstopk<<<NB, 256, 0, stream>>>(lat, tv, ti, accum);
  gemm_bf16<1><<<dim3(ND / 128, NB / 128, 4), 256, 0, stream>>>(
      lat, Wdt, NF, NF / 4, nullptr, RP);
  l2full<<<2048, 256, 0, stream>>>(RP, bdec, X, accum);
  sdecode<<<NB, 256, 0, stream>>>(tv, ti, Wdb, bdec, X, xrec, accum);
  zeroscatter<<<NB, 256, 0, stream>>>(tv, ti, acts);
  finalize<<<1, 64, 0, stream>>>(accum, scal);
}